// Round 1
// baseline (11624.873 us; speedup 1.0000x reference)
//
#include <hip/hip_runtime.h>

#define B_ 64
#define S_ 512
#define I_ 512
#define H_ 512

typedef unsigned short u16;
typedef unsigned int   u32;

typedef __attribute__((ext_vector_type(8))) short   bf16x8;
typedef __attribute__((ext_vector_type(4))) float   f32x4;
typedef __attribute__((ext_vector_type(2))) _Float16 h2_t;

// ---------- helpers ----------
__device__ inline u16 f2bf(float f) {            // RNE fp32 -> bf16 bits
  u32 u = __builtin_bit_cast(u32, f);
  u32 r = (u + 0x7fffu + ((u >> 16) & 1u)) >> 16;
  return (u16)r;
}
__device__ inline u32 pk2h(float a, float b) {   // pack two f32 -> half2 bits
  _Float16 x = (_Float16)a, y = (_Float16)b;
  return (u32)__builtin_bit_cast(u16, x) | ((u32)__builtin_bit_cast(u16, y) << 16);
}
__device__ inline float dot2(u32 w, u32 h, float acc) {
#if __has_builtin(__builtin_amdgcn_fdot2)
  return __builtin_amdgcn_fdot2(__builtin_bit_cast(h2_t, w),
                                __builtin_bit_cast(h2_t, h), acc, false);
#else
  h2_t a = __builtin_bit_cast(h2_t, w), b = __builtin_bit_cast(h2_t, h);
  return acc + (float)a[0] * (float)b[0] + (float)a[1] * (float)b[1];
#endif
}
__device__ inline float sigmoidf_(float x) { return 1.f / (1.f + __expf(-x)); }
__device__ inline float tanhf_(float x) {
  float e = __expf(-2.f * fabsf(x));
  float t = (1.f - e) / (1.f + e);
  return copysignf(t, x);
}

// ---------- kernel 1: x fp32 -> bf16 ----------
__global__ void k_convert_x(const float4* __restrict__ x, uint2* __restrict__ xb) {
  int i = blockIdx.x * 256 + threadIdx.x;   // covers B*S*I/4 = 4,194,304
  float4 v = x[i];
  uint2 o;
  o.x = (u32)f2bf(v.x) | ((u32)f2bf(v.y) << 16);
  o.y = (u32)f2bf(v.z) | ((u32)f2bf(v.w) << 16);
  xb[i] = o;
}

// ---------- kernel 2: split/convert W ----------
// Wxb[g][n][k] = bf16(W_g[n, k])                       (k < 512, input half)
// Wt [g][j2][k2] = half4{ W[2k2][512+2j2], W[2k2][512+2j2+1],
//                         W[2k2+1][512+2j2], W[2k2+1][512+2j2+1] }  (transposed, pair-packed)
__global__ void k_convert_w(const float* __restrict__ Wr, const float* __restrict__ Wz,
                            const float* __restrict__ Wh,
                            u16* __restrict__ Wxb, uint2* __restrict__ Wt) {
  int g = blockIdx.y;
  const float* Ws = (g == 0) ? Wr : ((g == 1) ? Wz : Wh);
  int idx = blockIdx.x * 256 + threadIdx.x;
  if (idx < 512 * 512) {
    int n = idx >> 9, k = idx & 511;
    Wxb[g * 262144 + idx] = f2bf(Ws[(size_t)n * 1024 + k]);
  } else {
    int i  = idx - 262144;           // < 65536
    int j2 = i >> 8, k2 = i & 255;
    const float* r0 = Ws + (size_t)(2 * k2) * 1024 + 512 + 2 * j2;
    const float* r1 = Ws + (size_t)(2 * k2 + 1) * 1024 + 512 + 2 * j2;
    uint2 o;
    o.x = pk2h(r0[0], r0[1]);
    o.y = pk2h(r1[0], r1[1]);
    Wt[(size_t)g * 65536 + j2 * 256 + k2] = o;
  }
}

// ---------- kernel 3: projection GEMM (bf16 MFMA) ----------
// P[g][m][n] = f16( sum_k Xb[m,k]*Wxb[g][n,k] + bias_g[n] ),  m = b*512+s
__global__ __launch_bounds__(256) void k_proj_gemm(
    const u16* __restrict__ Xb,      // [32768][512] bf16
    const u16* __restrict__ Wxb,     // [3][512][512] bf16
    const float* __restrict__ br, const float* __restrict__ bz, const float* __restrict__ bh,
    u16* __restrict__ P)             // [3][32768][512] f16
{
  const int g  = blockIdx.z;
  const int bm = blockIdx.x * 64;
  const int bn = blockIdx.y * 64;
  __shared__ u16 As[64][32];
  __shared__ u16 Bs[64][32];
  const int tid  = threadIdx.x;
  const int lane = tid & 63;
  const int wm   = (tid >> 6) >> 1;     // 0..1
  const int wn   = (tid >> 6) & 1;      // 0..1
  const int srow = tid >> 2;            // 0..63
  const int scol = (tid & 3) * 8;       // 0,8,16,24
  const u16* Wg = Wxb + (size_t)g * (512 * 512);

  f32x4 zero4 = {0.f, 0.f, 0.f, 0.f};
  f32x4 acc[2][2];
  acc[0][0] = zero4; acc[0][1] = zero4; acc[1][0] = zero4; acc[1][1] = zero4;

  for (int k0 = 0; k0 < 512; k0 += 32) {
    __syncthreads();
    *(int4*)(&As[srow][scol]) = *(const int4*)(Xb + (size_t)(bm + srow) * 512 + k0 + scol);
    *(int4*)(&Bs[srow][scol]) = *(const int4*)(Wg + (size_t)(bn + srow) * 512 + k0 + scol);
    __syncthreads();
#pragma unroll
    for (int mi = 0; mi < 2; ++mi) {
      bf16x8 a = *(const bf16x8*)(&As[wm * 32 + mi * 16 + (lane & 15)][(lane >> 4) * 8]);
#pragma unroll
      for (int ni = 0; ni < 2; ++ni) {
        bf16x8 b = *(const bf16x8*)(&Bs[wn * 32 + ni * 16 + (lane & 15)][(lane >> 4) * 8]);
        acc[mi][ni] = __builtin_amdgcn_mfma_f32_16x16x32_bf16(a, b, acc[mi][ni], 0, 0, 0);
      }
    }
  }
  const float* bias = (g == 0) ? br : ((g == 1) ? bz : bh);
  u16* Pg = P + (size_t)g * ((size_t)32768 * 512);
#pragma unroll
  for (int mi = 0; mi < 2; ++mi)
#pragma unroll
    for (int ni = 0; ni < 2; ++ni) {
      int col  = bn + wn * 32 + ni * 16 + (lane & 15);
      float bv = bias[col];
#pragma unroll
      for (int r = 0; r < 4; ++r) {
        int row = bm + wm * 32 + mi * 16 + (lane >> 4) * 4 + r;
        float v = acc[mi][ni][r] + bv;
        Pg[(size_t)row * 512 + col] = __builtin_bit_cast(u16, (_Float16)v);
      }
    }
}

// ---------- kernel 4: sequential GRU scan ----------
// One block = 2 batches for all 512 steps. 512 threads:
//   phase1: waves 0-3 compute r (outputs 2u,2u+1), waves 4-7 compute z.
//   phase2: all waves compute htilde partials (j split in half), reduce via LDS.
__global__ __launch_bounds__(512) void k_gru_scan(
    const float* __restrict__ h0,
    const u16*  __restrict__ P,       // [3][B*S][512] f16 bits
    const uint2* __restrict__ Wt,     // [3][256][256] pair-packed transposed
    float* __restrict__ y,            // [B][S][512]
    float* __restrict__ hlast)        // [B][512]
{
  const int  b0  = blockIdx.x * 2;
  const int  t   = threadIdx.x;
  const int  u   = t & 255;
  const bool low = (t < 256);
  const size_t PJ = (size_t)B_ * S_ * H_;

  __shared__ uint2  h_pk[256];    // half2 x2: {h[b0][2j2..+1], h[b0+1][2j2..+1]}
  __shared__ uint2  rh_pk[256];   // same layout for r*h
  __shared__ float2 zf2[2][256];
  __shared__ float2 ps2[2][256];

  float hr00 = 0.f, hr01 = 0.f, hr10 = 0.f, hr11 = 0.f;
  if (low) {
    hr00 = h0[(size_t)(b0 + 0) * H_ + 2 * u];
    hr01 = h0[(size_t)(b0 + 0) * H_ + 2 * u + 1];
    hr10 = h0[(size_t)(b0 + 1) * H_ + 2 * u];
    hr11 = h0[(size_t)(b0 + 1) * H_ + 2 * u + 1];
    uint2 hp; hp.x = pk2h(hr00, hr01); hp.y = pk2h(hr10, hr11);
    h_pk[u] = hp;
  }
  __syncthreads();

  const uint2* Wg  = Wt + (size_t)(low ? 0 : 1) * 65536 + u;              // r or z
  const uint2* Wht = Wt + (size_t)2 * 65536 + u + (low ? 0 : 128 * 256);  // htilde, j-half
  const u16*   Pg  = P + (size_t)(low ? 0 : 1) * PJ;
  const u16*   Ph  = P + (size_t)2 * PJ;
  const int jbase  = low ? 0 : 128;

  for (int ts = 0; ts < S_; ++ts) {
    // ---- phase 1: r / z GEMV ----
    float a00 = 0.f, a01 = 0.f, a10 = 0.f, a11 = 0.f;
#pragma unroll 8
    for (int j2 = 0; j2 < 256; ++j2) {
      uint2 w  = Wg[j2 * 256];
      uint2 hv = h_pk[j2];
      a00 = dot2(w.x, hv.x, a00);
      a01 = dot2(w.y, hv.x, a01);
      a10 = dot2(w.x, hv.y, a10);
      a11 = dot2(w.y, hv.y, a11);
    }
    {
      const u16* p0 = Pg + ((size_t)(b0 + 0) * S_ + ts) * H_ + 2 * u;
      const u16* p1 = Pg + ((size_t)(b0 + 1) * S_ + ts) * H_ + 2 * u;
      h2_t q0 = __builtin_bit_cast(h2_t, *(const u32*)p0);
      h2_t q1 = __builtin_bit_cast(h2_t, *(const u32*)p1);
      float v00 = sigmoidf_(a00 + (float)q0[0]);
      float v01 = sigmoidf_(a01 + (float)q0[1]);
      float v10 = sigmoidf_(a10 + (float)q1[0]);
      float v11 = sigmoidf_(a11 + (float)q1[1]);
      if (low) {
        uint2 rp; rp.x = pk2h(v00 * hr00, v01 * hr01); rp.y = pk2h(v10 * hr10, v11 * hr11);
        rh_pk[u] = rp;
      } else {
        float2 z0 = {v00, v01}, z1 = {v10, v11};
        zf2[0][u] = z0; zf2[1][u] = z1;
      }
    }
    __syncthreads();

    // ---- phase 2: htilde GEMV (each half does 128 of the 256 j2) ----
    float c00 = 0.f, c01 = 0.f, c10 = 0.f, c11 = 0.f;
#pragma unroll 8
    for (int j2 = 0; j2 < 128; ++j2) {
      uint2 w  = Wht[j2 * 256];
      uint2 rv = rh_pk[jbase + j2];
      c00 = dot2(w.x, rv.x, c00);
      c01 = dot2(w.y, rv.x, c01);
      c10 = dot2(w.x, rv.y, c10);
      c11 = dot2(w.y, rv.y, c11);
    }
    if (!low) {
      float2 s0 = {c00, c01}, s1 = {c10, c11};
      ps2[0][u] = s0; ps2[1][u] = s1;
    }
    __syncthreads();

    if (low) {
      const u16* p0 = Ph + ((size_t)(b0 + 0) * S_ + ts) * H_ + 2 * u;
      const u16* p1 = Ph + ((size_t)(b0 + 1) * S_ + ts) * H_ + 2 * u;
      h2_t q0 = __builtin_bit_cast(h2_t, *(const u32*)p0);
      h2_t q1 = __builtin_bit_cast(h2_t, *(const u32*)p1);
      float2 pp0 = ps2[0][u], pp1 = ps2[1][u];
      float s00 = c00 + pp0.x + (float)q0[0];
      float s01 = c01 + pp0.y + (float)q0[1];
      float s10 = c10 + pp1.x + (float)q1[0];
      float s11 = c11 + pp1.y + (float)q1[1];
      float t00 = tanhf_(s00), t01 = tanhf_(s01), t10 = tanhf_(s10), t11 = tanhf_(s11);
      float2 zz0 = zf2[0][u], zz1 = zf2[1][u];
      hr00 = zz0.x * t00 + (1.f - zz0.x) * hr00;
      hr01 = zz0.y * t01 + (1.f - zz0.y) * hr01;
      hr10 = zz1.x * t10 + (1.f - zz1.x) * hr10;
      hr11 = zz1.y * t11 + (1.f - zz1.y) * hr11;
      uint2 hp; hp.x = pk2h(hr00, hr01); hp.y = pk2h(hr10, hr11);
      h_pk[u] = hp;
      float2 y0 = {hr00, hr01}, y1 = {hr10, hr11};
      *(float2*)(y + ((size_t)(b0 + 0) * S_ + ts) * H_ + 2 * u) = y0;
      *(float2*)(y + ((size_t)(b0 + 1) * S_ + ts) * H_ + 2 * u) = y1;
    }
    __syncthreads();
  }

  if (low) {
    hlast[(size_t)(b0 + 0) * H_ + 2 * u]     = hr00;
    hlast[(size_t)(b0 + 0) * H_ + 2 * u + 1] = hr01;
    hlast[(size_t)(b0 + 1) * H_ + 2 * u]     = hr10;
    hlast[(size_t)(b0 + 1) * H_ + 2 * u + 1] = hr11;
  }
}

// ---------- host ----------
extern "C" void kernel_launch(void* const* d_in, const int* in_sizes, int n_in,
                              void* d_out, int out_size, void* d_ws, size_t ws_size,
                              hipStream_t stream) {
  const float* x  = (const float*)d_in[0];
  const float* h0 = (const float*)d_in[1];
  const float* Wr = (const float*)d_in[2];
  const float* br = (const float*)d_in[3];
  const float* Wz = (const float*)d_in[4];
  const float* bz = (const float*)d_in[5];
  const float* Wh = (const float*)d_in[6];
  const float* bh = (const float*)d_in[7];

  char* ws = (char*)d_ws;
  // layout: Xb 32MB | Wxb 1.5MB | Wt 1.5MB | P 96MB  (total ~131MB)
  u16*   Xb  = (u16*)ws;
  u16*   Wxb = (u16*)(ws + 33554432);
  uint2* Wt  = (uint2*)(ws + 35127296);
  u16*   P   = (u16*)(ws + 36700160);

  float* y     = (float*)d_out;
  float* hlast = y + (size_t)B_ * S_ * H_;

  k_convert_x<<<dim3(16384), dim3(256), 0, stream>>>((const float4*)x, (uint2*)Xb);
  k_convert_w<<<dim3(1280, 3), dim3(256), 0, stream>>>(Wr, Wz, Wh, Wxb, Wt);
  k_proj_gemm<<<dim3(512, 8, 3), dim3(256), 0, stream>>>(Xb, Wxb, br, bz, bh, P);
  k_gru_scan<<<dim3(32), dim3(512), 0, stream>>>(h0, P, Wt, y, hlast);
}